// Round 3
// baseline (640.238 us; speedup 1.0000x reference)
//
#include <hip/hip_runtime.h>

// Problem constants (from reference)
constexpr int BB = 4;
constexpr int CHN = 64;
constexpr int HH = 128;
constexpr int WW = 128;
constexpr int NN = HH * WW;            // 16384 query positions
constexpr int MM = (HH / 2) * (WW / 2); // 4096 key positions
constexpr int CQ = 8;   // C/8
constexpr int CV = 32;  // C/2

constexpr int MC = 128;           // keys per LDS chunk
constexpr int NCHUNK = MM / MC;   // 32
constexpr int CALLS_PER_CHUNK = (MC * CQ * 4 + MC * CV * 4) / 1024; // 4 + 16 = 20

// ---------------------------------------------------------------------------
// async global -> LDS, 16 bytes per lane (lane i writes lds_base + i*16)
__device__ __forceinline__ void async16(void* lds_base, const void* gsrc) {
    __builtin_amdgcn_global_load_lds(
        (const __attribute__((address_space(1))) unsigned int*)gsrc,
        (__attribute__((address_space(3))) unsigned int*)lds_base,
        16, 0, 0);
}

// ---------------------------------------------------------------------------
// Kernel P: pooled 1x1 convs.  phi_t[b][m][0..7], g_t[b][m][0..31]
// One lane per pooled position m. Weights staged in LDS, broadcast reads.
__global__ __launch_bounds__(64)
void pool_conv_kernel(const float* __restrict__ x,
                      const float* __restrict__ w_phi,
                      const float* __restrict__ w_g,
                      float* __restrict__ phi_t,
                      float* __restrict__ g_t) {
    __shared__ __align__(16) float wlds[40][64];  // rows 0..7 = w_phi, 8..39 = w_g
    const int lane = threadIdx.x;
    float* w0 = &wlds[0][0];
    for (int i = lane; i < CQ * CHN; i += 64) w0[i] = w_phi[i];
    for (int i = lane; i < CV * CHN; i += 64) w0[CQ * CHN + i] = w_g[i];
    __syncthreads();

    const int b = blockIdx.x >> 6;                 // MM/64 = 64 blocks per batch
    const int m = ((blockIdx.x & 63) << 6) + lane; // [0, 4096)
    const int hp = m >> 6;          // W/2 = 64
    const int wp = m & 63;
    const int n00 = hp * (2 * WW) + 2 * wp;
    const int offs[4] = { n00, n00 + 1, n00 + WW, n00 + WW + 1 };

    const float* xb = x + (size_t)b * CHN * NN;

    float best[40];
#pragma unroll
    for (int k = 0; k < 40; ++k) best[k] = -3.402823466e38f;

    for (int p = 0; p < 4; ++p) {
        const float* xp = xb + offs[p];
        float acc[40];
#pragma unroll
        for (int k = 0; k < 40; ++k) acc[k] = 0.f;
        for (int c = 0; c < CHN; c += 4) {
            const float x0 = xp[(size_t)(c + 0) * NN];
            const float x1 = xp[(size_t)(c + 1) * NN];
            const float x2 = xp[(size_t)(c + 2) * NN];
            const float x3 = xp[(size_t)(c + 3) * NN];
#pragma unroll
            for (int k = 0; k < 40; ++k) {
                const float4 w4 = *(const float4*)&wlds[k][c];
                acc[k] = fmaf(w4.x, x0, acc[k]);
                acc[k] = fmaf(w4.y, x1, acc[k]);
                acc[k] = fmaf(w4.z, x2, acc[k]);
                acc[k] = fmaf(w4.w, x3, acc[k]);
            }
        }
#pragma unroll
        for (int k = 0; k < 40; ++k) best[k] = fmaxf(best[k], acc[k]);
    }

    float* pout = phi_t + ((size_t)b * MM + m) * CQ;
#pragma unroll
    for (int k = 0; k < CQ; ++k) pout[k] = best[k];
    float* gout = g_t + ((size_t)b * MM + m) * CV;
#pragma unroll
    for (int k = 0; k < CV; ++k) gout[k] = best[CQ + k];
}

// ---------------------------------------------------------------------------
// Kernel A: fused theta + softmax(no-max) + PV + output proj + residual.
// 1 wave per block, 1 query per lane. phi/g double-buffered LDS chunks.
__device__ __forceinline__ void issue_chunk(float* phi_d, float* g_d,
                                            const float* phib, const float* gbb,
                                            int t, int lane) {
    const char* ps = (const char*)(phib + (size_t)t * MC * CQ);
    const char* gs = (const char*)(gbb + (size_t)t * MC * CV);
    char* pd = (char*)phi_d;
    char* gd = (char*)g_d;
#pragma unroll
    for (int i = 0; i < (MC * CQ * 4) / 1024; ++i)   // 4 calls
        async16(pd + i * 1024, ps + i * 1024 + lane * 16);
#pragma unroll
    for (int i = 0; i < (MC * CV * 4) / 1024; ++i)   // 16 calls
        async16(gd + i * 1024, gs + i * 1024 + lane * 16);
}

__global__ __launch_bounds__(64)
void attn_kernel(const float* __restrict__ x,
                 const float* __restrict__ w_theta,
                 const float* __restrict__ w_o,
                 const float* __restrict__ gamma_p,
                 const float* __restrict__ phi_t,
                 const float* __restrict__ g_t,
                 float* __restrict__ out) {
    __shared__ __align__(16) float phi_s[2][MC * CQ];  // 2 x 4KB
    __shared__ __align__(16) float g_s[2][MC * CV];    // 2 x 16KB

    const int lane = threadIdx.x;
    const int b = blockIdx.x >> 8;                  // NN/64 = 256 blocks per batch
    const int q = ((blockIdx.x & 255) << 6) + lane; // [0, 16384)

    // ---- theta for this query: th[o] = sum_c w_theta[o][c] * x[b][c][q]
    const float* xq = x + (size_t)b * CHN * NN + q;
    float th[CQ];
#pragma unroll
    for (int o = 0; o < CQ; ++o) th[o] = 0.f;
    for (int c = 0; c < CHN; ++c) {
        const float xv = xq[(size_t)c * NN];
#pragma unroll
        for (int o = 0; o < CQ; ++o)
            th[o] = fmaf(w_theta[o * CHN + c], xv, th[o]);
    }

    const float* phib = phi_t + (size_t)b * MM * CQ;
    const float* gbb  = g_t  + (size_t)b * MM * CV;

    float acc[CV];
#pragma unroll
    for (int k = 0; k < CV; ++k) acc[k] = 0.f;
    float ssum = 0.f;

    // prologue: chunk 0 -> buf 0
    issue_chunk(phi_s[0], g_s[0], phib, gbb, 0, lane);

    for (int t = 0; t < NCHUNK; ++t) {
        const int buf = t & 1;
        if (t + 1 < NCHUNK) {
            // previous reads of buf^1 are fully retired (their FMAs executed)
            asm volatile("s_waitcnt lgkmcnt(0)" ::: "memory");
            issue_chunk(phi_s[buf ^ 1], g_s[buf ^ 1], phib, gbb, t + 1, lane);
            asm volatile("s_waitcnt vmcnt(20)" ::: "memory"); // chunk t landed
        } else {
            asm volatile("s_waitcnt vmcnt(0)" ::: "memory");
        }
        const float* ph = phi_s[buf];
        const float* gg = g_s[buf];
#pragma unroll 2
        for (int mi = 0; mi < MC; ++mi) {
            const float4 p0 = *(const float4*)(ph + mi * CQ);
            const float4 p1 = *(const float4*)(ph + mi * CQ + 4);
            const float s =
                (fmaf(th[0], p0.x, th[1] * p0.y) + fmaf(th[2], p0.z, th[3] * p0.w)) +
                (fmaf(th[4], p1.x, th[5] * p1.y) + fmaf(th[6], p1.z, th[7] * p1.w));
            const float e = __expf(s);
            ssum += e;
            const float4* gv = (const float4*)(gg + mi * CV);
#pragma unroll
            for (int k = 0; k < 8; ++k) {
                const float4 gk = gv[k];
                acc[4 * k + 0] = fmaf(e, gk.x, acc[4 * k + 0]);
                acc[4 * k + 1] = fmaf(e, gk.y, acc[4 * k + 1]);
                acc[4 * k + 2] = fmaf(e, gk.z, acc[4 * k + 2]);
                acc[4 * k + 3] = fmaf(e, gk.w, acc[4 * k + 3]);
            }
        }
    }

    // ---- finish softmax + output projection + residual
    const float inv = 1.0f / ssum;
    float om[CV];
#pragma unroll
    for (int k = 0; k < CV; ++k) om[k] = acc[k] * inv;

    const float gm = gamma_p[0];
    const float* xb = x + (size_t)b * CHN * NN + q;
    for (int oc = 0; oc < CHN; ++oc) {
        float v = 0.f;
#pragma unroll
        for (int c = 0; c < CV; ++c)
            v = fmaf(w_o[oc * CV + c], om[c], v);
        const size_t idx = (size_t)oc * NN;
        out[(size_t)b * CHN * NN + q + idx] = fmaf(gm, v, xb[idx]);
    }
}

// ---------------------------------------------------------------------------
extern "C" void kernel_launch(void* const* d_in, const int* in_sizes, int n_in,
                              void* d_out, int out_size, void* d_ws, size_t ws_size,
                              hipStream_t stream) {
    const float* x       = (const float*)d_in[0];
    const float* w_theta = (const float*)d_in[1];
    const float* w_phi   = (const float*)d_in[2];
    const float* w_g     = (const float*)d_in[3];
    const float* w_o     = (const float*)d_in[4];
    const float* gamma   = (const float*)d_in[5];
    float* out = (float*)d_out;

    float* phi_t = (float*)d_ws;                       // B*M*8  floats
    float* g_t   = phi_t + (size_t)BB * MM * CQ;       // B*M*32 floats

    pool_conv_kernel<<<dim3(BB * MM / 64), dim3(64), 0, stream>>>(
        x, w_phi, w_g, phi_t, g_t);

    attn_kernel<<<dim3(BB * NN / 64), dim3(64), 0, stream>>>(
        x, w_theta, w_o, gamma, phi_t, g_t, out);
}

// Round 5
// 565.892 us; speedup vs baseline: 1.1314x; 1.1314x over previous
//
#include <hip/hip_runtime.h>

// Problem constants (from reference)
constexpr int BB = 4;
constexpr int CHN = 64;
constexpr int HH = 128;
constexpr int WW = 128;
constexpr int NN = HH * WW;             // 16384 query positions
constexpr int MM = (HH / 2) * (WW / 2); // 4096 key positions
constexpr int CQ = 8;   // C/8
constexpr int CV = 32;  // C/2

constexpr int MC = 32;            // keys per LDS chunk
constexpr int NCHUNK = MM / MC;   // 128
constexpr int QPW = 16;           // queries per wave
// 5 global_load_lds calls per chunk: 1 (phi, 1KB) + 4 (g, 4KB)

// ---------------------------------------------------------------------------
// async global -> LDS, 16 bytes per lane (lane i writes lds_base + i*16)
__device__ __forceinline__ void async16(void* lds_base, const void* gsrc) {
    __builtin_amdgcn_global_load_lds(
        (const __attribute__((address_space(1))) unsigned int*)gsrc,
        (__attribute__((address_space(3))) unsigned int*)lds_base,
        16, 0, 0);
}

// ---------------------------------------------------------------------------
// Kernel P: pooled 1x1 convs.  phi_t[b][m][0..7] plain; g_t stored with the
// 16B-chunk XOR swizzle (chunk c8 of row m lands at c8 ^ (m&3)) so kernel A's
// 4 key-lanes hit disjoint LDS bank groups.
__global__ __launch_bounds__(64)
void pool_conv_kernel(const float* __restrict__ x,
                      const float* __restrict__ w_phi,
                      const float* __restrict__ w_g,
                      float* __restrict__ phi_t,
                      float* __restrict__ g_t) {
    __shared__ __align__(16) float wlds[40][64];  // rows 0..7 = w_phi, 8..39 = w_g
    const int lane = threadIdx.x;
    float* w0 = &wlds[0][0];
    for (int i = lane; i < CQ * CHN; i += 64) w0[i] = w_phi[i];
    for (int i = lane; i < CV * CHN; i += 64) w0[CQ * CHN + i] = w_g[i];
    __syncthreads();

    const int b = blockIdx.x >> 6;                 // MM/64 = 64 blocks per batch
    const int m = ((blockIdx.x & 63) << 6) + lane; // [0, 4096)
    const int hp = m >> 6;          // W/2 = 64
    const int wp = m & 63;
    const int n00 = hp * (2 * WW) + 2 * wp;
    const int offs[4] = { n00, n00 + 1, n00 + WW, n00 + WW + 1 };

    const float* xb = x + (size_t)b * CHN * NN;

    float best[40];
#pragma unroll
    for (int k = 0; k < 40; ++k) best[k] = -3.402823466e38f;

    for (int p = 0; p < 4; ++p) {
        const float* xp = xb + offs[p];
        float acc[40];
#pragma unroll
        for (int k = 0; k < 40; ++k) acc[k] = 0.f;
        for (int c = 0; c < CHN; c += 4) {
            const float x0 = xp[(size_t)(c + 0) * NN];
            const float x1 = xp[(size_t)(c + 1) * NN];
            const float x2 = xp[(size_t)(c + 2) * NN];
            const float x3 = xp[(size_t)(c + 3) * NN];
#pragma unroll
            for (int k = 0; k < 40; ++k) {
                const float4 w4 = *(const float4*)&wlds[k][c];
                acc[k] = fmaf(w4.x, x0, acc[k]);
                acc[k] = fmaf(w4.y, x1, acc[k]);
                acc[k] = fmaf(w4.z, x2, acc[k]);
                acc[k] = fmaf(w4.w, x3, acc[k]);
            }
        }
#pragma unroll
        for (int k = 0; k < 40; ++k) best[k] = fmaxf(best[k], acc[k]);
    }

    float* pout = phi_t + ((size_t)b * MM + m) * CQ;
#pragma unroll
    for (int k = 0; k < CQ; ++k) pout[k] = best[k];

    float4* gout4 = (float4*)(g_t + ((size_t)b * MM + m) * CV);
    const int sw = m & 3;
#pragma unroll
    for (int c8 = 0; c8 < 8; ++c8)
        gout4[c8 ^ sw] = make_float4(best[CQ + 4 * c8 + 0], best[CQ + 4 * c8 + 1],
                                     best[CQ + 4 * c8 + 2], best[CQ + 4 * c8 + 3]);
}

// ---------------------------------------------------------------------------
// Kernel A: 16 queries/wave, 4 key-lanes/query (lane j handles keys m%4==j).
// phi/g double-buffered LDS chunks via global_load_lds, counted vmcnt.
__device__ __forceinline__ void issue_chunk(float* phi_d, float* g_d,
                                            const float* phib, const float* gbb,
                                            int t, int lane) {
    const char* ps = (const char*)(phib + (size_t)t * MC * CQ);
    const char* gs = (const char*)(gbb + (size_t)t * MC * CV);
    async16((char*)phi_d, ps + lane * 16);                 // 1KB
#pragma unroll
    for (int i = 0; i < 4; ++i)                            // 4KB
        async16((char*)g_d + i * 1024, gs + i * 1024 + lane * 16);
}

__global__ __launch_bounds__(64, 4)
void attn_kernel(const float* __restrict__ x,
                 const float* __restrict__ w_theta,
                 const float* __restrict__ w_o,
                 const float* __restrict__ gamma_p,
                 const float* __restrict__ phi_t,
                 const float* __restrict__ g_t,
                 float* __restrict__ out) {
    __shared__ __align__(16) float phi_s[2][MC * CQ];  // 2 x 1KB
    __shared__ __align__(16) float g_s[2][MC * CV];    // 2 x 4KB  -> 10,240B total

    const int lane = threadIdx.x;
    const int j = lane & 3;        // key-lane within query group
    const int qg = lane >> 2;      // query slot [0,16)
    const int b = blockIdx.x >> 10;                    // NN/QPW = 1024 blocks/batch
    const int q = ((blockIdx.x & 1023) * QPW) + qg;    // [0, 16384)

    // ---- theta for this query (computed redundantly by the 4 key-lanes)
    const float* xq = x + (size_t)b * CHN * NN + q;
    float th[CQ];
#pragma unroll
    for (int o = 0; o < CQ; ++o) th[o] = 0.f;
    for (int c = 0; c < CHN; ++c) {
        const float xv = xq[(size_t)c * NN];
#pragma unroll
        for (int o = 0; o < CQ; ++o)
            th[o] = fmaf(w_theta[o * CHN + c], xv, th[o]);
    }

    const float* phib = phi_t + (size_t)b * MM * CQ;
    const float* gbb  = g_t  + (size_t)b * MM * CV;

    float acc[CV];
#pragma unroll
    for (int k = 0; k < CV; ++k) acc[k] = 0.f;
    float ssum = 0.f;

    issue_chunk(phi_s[0], g_s[0], phib, gbb, 0, lane);

    for (int t = 0; t < NCHUNK; ++t) {
        const int buf = t & 1;
        if (t + 1 < NCHUNK) {
            // reads of buf^1 (iteration t-1) already retired into VGPRs
            asm volatile("s_waitcnt lgkmcnt(0)" ::: "memory");
            issue_chunk(phi_s[buf ^ 1], g_s[buf ^ 1], phib, gbb, t + 1, lane);
            asm volatile("s_waitcnt vmcnt(5)" ::: "memory"); // chunk t landed
        } else {
            asm volatile("s_waitcnt vmcnt(0)" ::: "memory");
        }
        const float* ph = phi_s[buf];
        const float* gg = g_s[buf];
#pragma unroll
        for (int st = 0; st < MC / 4; ++st) {       // 8 key-steps, key ml = st*4+j
            const int ml = st * 4 + j;
            const float4 p0 = *(const float4*)(ph + ml * CQ);
            const float4 p1 = *(const float4*)(ph + ml * CQ + 4);
            const float s =
                (fmaf(th[0], p0.x, th[1] * p0.y) + fmaf(th[2], p0.z, th[3] * p0.w)) +
                (fmaf(th[4], p1.x, th[5] * p1.y) + fmaf(th[6], p1.z, th[7] * p1.w));
            const float e = __expf(s);
            ssum += e;
            const float4* gr = (const float4*)(gg + ml * CV);
#pragma unroll
            for (int c8 = 0; c8 < 8; ++c8) {
                const float4 gk = gr[c8 ^ j];       // undo store-side swizzle
                acc[4 * c8 + 0] = fmaf(e, gk.x, acc[4 * c8 + 0]);
                acc[4 * c8 + 1] = fmaf(e, gk.y, acc[4 * c8 + 1]);
                acc[4 * c8 + 2] = fmaf(e, gk.z, acc[4 * c8 + 2]);
                acc[4 * c8 + 3] = fmaf(e, gk.w, acc[4 * c8 + 3]);
            }
        }
    }

    // ---- reduce the 4 key-lanes (xor masks 1,2 stay inside the quad)
#pragma unroll
    for (int k = 0; k < CV; ++k) {
        acc[k] += __shfl_xor(acc[k], 1);
        acc[k] += __shfl_xor(acc[k], 2);
    }
    ssum += __shfl_xor(ssum, 1);
    ssum += __shfl_xor(ssum, 2);

    const float inv = 1.0f / ssum;
    float om[CV];
#pragma unroll
    for (int k = 0; k < CV; ++k) om[k] = acc[k] * inv;

    const float gm = gamma_p[0];
    const float* xb = x + (size_t)b * CHN * NN + q;
    float* ob = out + (size_t)b * CHN * NN + q;
    for (int oc = 0; oc < CHN; ++oc) {           // wave-uniform w_o -> s_loads
        float v = 0.f;
#pragma unroll
        for (int c = 0; c < CV; ++c)
            v = fmaf(w_o[oc * CV + c], om[c], v);
        if ((oc >> 4) == j)                      // each key-lane stores 16 oc
            ob[(size_t)oc * NN] = fmaf(gm, v, xb[(size_t)oc * NN]);
    }
}

// ---------------------------------------------------------------------------
extern "C" void kernel_launch(void* const* d_in, const int* in_sizes, int n_in,
                              void* d_out, int out_size, void* d_ws, size_t ws_size,
                              hipStream_t stream) {
    const float* x       = (const float*)d_in[0];
    const float* w_theta = (const float*)d_in[1];
    const float* w_phi   = (const float*)d_in[2];
    const float* w_g     = (const float*)d_in[3];
    const float* w_o     = (const float*)d_in[4];
    const float* gamma   = (const float*)d_in[5];
    float* out = (float*)d_out;

    float* phi_t = (float*)d_ws;                       // B*M*8  floats
    float* g_t   = phi_t + (size_t)BB * MM * CQ;       // B*M*32 floats (swizzled)

    pool_conv_kernel<<<dim3(BB * MM / 64), dim3(64), 0, stream>>>(
        x, w_phi, w_g, phi_t, g_t);

    attn_kernel<<<dim3(BB * NN / QPW), dim3(64), 0, stream>>>(
        x, w_theta, w_o, gamma, phi_t, g_t, out);
}

// Round 9
// 224.428 us; speedup vs baseline: 2.8528x; 2.5215x over previous
//
#include <hip/hip_runtime.h>

typedef unsigned int uint;
typedef unsigned short ushort;
typedef __attribute__((ext_vector_type(8))) short bf16x8;
typedef __attribute__((ext_vector_type(16))) float f32x16;
typedef __attribute__((ext_vector_type(4))) uint uint4v;

constexpr int BB = 4, CHN = 64, HH = 128, WW = 128;
constexpr int NN = HH * WW;              // 16384 queries
constexpr int MM = (HH / 2) * (WW / 2);  // 4096 keys
constexpr float LOG2E = 1.44269504089f;

// workspace offsets in ushort units
constexpr size_t PHI_OFF = (size_t)BB * NN * 8;           // theta: [B][N][8]
constexpr size_t GT_OFF  = PHI_OFF + (size_t)BB * MM * 8; // phi:   [B][M][8]
// gT: [B][M/8][32][8]  (sigma-tiled transpose)

// ---------------------------------------------------------------------------
__device__ __forceinline__ void async16(void* lds_base, const void* gsrc) {
    __builtin_amdgcn_global_load_lds(
        (const __attribute__((address_space(1))) unsigned int*)gsrc,
        (__attribute__((address_space(3))) unsigned int*)lds_base,
        16, 0, 0);
}

__device__ __forceinline__ ushort bf16r(float f) {   // RNE f32->bf16
    uint u = __float_as_uint(f);
    u += 0x7fff + ((u >> 16) & 1);
    return (ushort)(u >> 16);
}

__device__ __forceinline__ uint pack2(float lo, float hi) {
    return (uint)bf16r(lo) | ((uint)bf16r(hi) << 16);
}

__device__ __forceinline__ bf16x8 pack8(const float* v) {
    union { uint4v u; bf16x8 x; } cv;
    cv.u = (uint4v){pack2(v[0], v[1]), pack2(v[2], v[3]),
                    pack2(v[4], v[5]), pack2(v[6], v[7])};
    return cv.x;
}

// ---------------------------------------------------------------------------
// prep: theta (scaled by log2e) at full res; pooled phi; pooled g transposed.
// Block = 64 lanes covering a 2-row x 32-col tile of full-res positions.
__global__ __launch_bounds__(64)
void prep_kernel(const float* __restrict__ x,
                 const float* __restrict__ w_theta,
                 const float* __restrict__ w_phi,
                 const float* __restrict__ w_g,
                 ushort* __restrict__ theta_t,
                 ushort* __restrict__ phi_b,
                 ushort* __restrict__ gTg) {
    __shared__ float wlds[48][64];  // 0..7 theta(*log2e), 8..15 phi, 16..47 g
    const int lane = threadIdx.x;
    float* wl = &wlds[0][0];
    for (int i = lane; i < 512; i += 64)  wl[i] = w_theta[i] * LOG2E;
    for (int i = lane; i < 512; i += 64)  wl[512 + i] = w_phi[i];
    for (int i = lane; i < 2048; i += 64) wl[1024 + i] = w_g[i];
    __syncthreads();

    const int bid = blockIdx.x;
    const int b = bid >> 8, tile = bid & 255;
    const int rp = tile >> 2, cb = tile & 3;     // row-pair, col-block
    const int h2 = lane >> 5, w2 = lane & 31;
    const int n = (2 * rp + h2) * WW + 32 * cb + w2;
    const float* xb = x + (size_t)b * CHN * NN + n;

    float acc[48];
#pragma unroll
    for (int k = 0; k < 48; ++k) acc[k] = 0.f;
#pragma unroll 4
    for (int c = 0; c < CHN; ++c) {
        const float xv = xb[(size_t)c * NN];
#pragma unroll
        for (int k = 0; k < 48; ++k) acc[k] = fmaf(wlds[k][c], xv, acc[k]);
    }

    // theta store (16B per lane)
    {
        uint4v tv = (uint4v){pack2(acc[0], acc[1]), pack2(acc[2], acc[3]),
                             pack2(acc[4], acc[5]), pack2(acc[6], acc[7])};
        *(uint4v*)(theta_t + ((size_t)b * NN + n) * 8) = tv;
    }

    // 2x2 max-pool of acc[8..47] across the quad {lane^1 (w), lane^32 (h)}
#pragma unroll
    for (int k = 8; k < 48; ++k) {
        float v = acc[k];
        v = fmaxf(v, __shfl_xor(v, 1));
        v = fmaxf(v, __shfl_xor(v, 32));
        acc[k] = v;
    }
    const int m = rp * 64 + 16 * cb + (w2 >> 1);

    if (h2 == 0 && (w2 & 1) == 0) {   // quad leader: phi row
        uint4v pv = (uint4v){pack2(acc[8], acc[9]),   pack2(acc[10], acc[11]),
                             pack2(acc[12], acc[13]), pack2(acc[14], acc[15])};
        *(uint4v*)(phi_b + ((size_t)b * MM + m) * 8) = pv;
    }
    // gT: [b][m>>3][c][m&7]; each quad lane stores 8 channels
    const int qidx = h2 * 2 + (w2 & 1);
    ushort* gb = gTg + (((size_t)b * (MM / 8) + (m >> 3)) * 32) * 8 + (m & 7);
#pragma unroll
    for (int j = 0; j < 8; ++j) {
        const int c = qidx * 8 + j;
        gb[(size_t)c * 8] = bf16r(acc[16 + c]);
    }
}

// ---------------------------------------------------------------------------
// attn: 4 waves/block, wave = 32-query tile; flash over M in 128-key chunks.
// P redistribution via per-wave padded LDS round-trip (C-layout store,
// B-frag contiguous read) — no permlane/cvt_pk primitives.
__global__ __launch_bounds__(256)
void attn_mfma(const float* __restrict__ x,
               const ushort* __restrict__ theta_t,
               const ushort* __restrict__ phi_b,
               const ushort* __restrict__ gTg,
               const float* __restrict__ w_o,
               const float* __restrict__ gamma_p,
               float* __restrict__ out) {
    __shared__ __align__(16) ushort phiL[2][1024];   // 128 m x 8, 2 KB each
    __shared__ __align__(16) ushort gL[2][4096];     // 16 sig x 32 c x 8, 8 KB each
    __shared__ __align__(16) ushort P_lds[4][32][40]; // per-wave [q][key], 80B rows

    const int tid = threadIdx.x;
    const int wv = tid >> 6, ln = tid & 63;
    const int lq = ln & 31, h = ln >> 5;
    const int b = blockIdx.x >> 7;            // 128 blocks per batch
    const int qt = blockIdx.x & 127;
    const int q0 = qt * 128 + wv * 32;

    // theta B-frag: lane holds theta[q0+lq][0..7] (h=1 half killed by A=0)
    union { uint4v u; bf16x8 v; } thc;
    thc.u = *(const uint4v*)(theta_t + ((size_t)b * NN + q0 + lq) * 8);
    const bf16x8 thB = thc.v;

    const char* phiGb = (const char*)(phi_b + (size_t)b * MM * 8);
    const char* gGb   = (const char*)(gTg + (size_t)b * MM * 32);

    f32x16 oacc, z16;
#pragma unroll
    for (int r = 0; r < 16; ++r) { oacc[r] = 0.f; z16[r] = 0.f; }
    float ssum = 0.f;

    auto stage = [&](int t, int buf) {
        for (int p = wv; p < 10; p += 4) {
            if (p < 2)
                async16(&phiL[buf][p * 512],
                        phiGb + (size_t)t * 2048 + p * 1024 + ln * 16);
            else
                async16(&gL[buf][(p - 2) * 512],
                        gGb + (size_t)t * 8192 + (p - 2) * 1024 + ln * 16);
        }
    };

    stage(0, 0);
    __syncthreads();   // vmcnt(0)+lgkmcnt(0)+barrier: chunk 0 resident

    for (int t = 0; t < MM / 128; ++t) {
        const int buf = t & 1;
        if (t < MM / 128 - 1) stage(t + 1, buf ^ 1);   // issue-early (T14)
        const ushort* pL = phiL[buf];
        const ushort* gg = gL[buf];
#pragma unroll
        for (int s = 0; s < 4; ++s) {
            // A = phi tile rows (m = s*32+lq), k = channel; h=1 half = K-pad 0
            bf16x8 aphi = {};
            if (h == 0) aphi = *(const bf16x8*)(pL + (s * 32 + lq) * 8);
            f32x16 S = __builtin_amdgcn_mfma_f32_32x32x16_bf16(aphi, thB, z16, 0, 0, 0);
            float e[16];
#pragma unroll
            for (int r = 0; r < 16; ++r) {
                e[r] = exp2f(fminf(S[r], 60.f));   // theta pre-scaled by log2e
                ssum += e[r];
            }
            // C-layout -> P_lds[q][key] (pairs are key,key+1: r even)
#pragma unroll
            for (int r = 0; r < 16; r += 2) {
                const int key = (r & 3) + 8 * (r >> 2) + 4 * h;
                *(uint*)&P_lds[wv][lq][key] = pack2(e[r], e[r + 1]);
            }
            // B-frags: lane (lq,h) needs P[q=lq][key = 8h+j (+16)]
            const bf16x8 B0 = *(const bf16x8*)&P_lds[wv][lq][8 * h];
            const bf16x8 B1 = *(const bf16x8*)&P_lds[wv][lq][16 + 8 * h];
            const bf16x8 g0 = *(const bf16x8*)(gg + ((s * 4 + h) * 256 + lq * 8));
            const bf16x8 g1 = *(const bf16x8*)(gg + ((s * 4 + 2 + h) * 256 + lq * 8));
            oacc = __builtin_amdgcn_mfma_f32_32x32x16_bf16(g0, B0, oacc, 0, 0, 0);
            oacc = __builtin_amdgcn_mfma_f32_32x32x16_bf16(g1, B1, oacc, 0, 0, 0);
        }
        __syncthreads();   // drains this wave's staged loads + joins waves
    }

    // ---- epilogue: normalize (+gamma), w_o projection via MFMA, residual
    ssum += __shfl_xor(ssum, 32);
    const float sc = gamma_p[0] / fmaxf(ssum, 1e-30f);
    float o16[16];
#pragma unroll
    for (int r = 0; r < 16; ++r) o16[r] = oacc[r] * sc;
    // O^T redistribution via the same LDS round-trip (keys -> channels)
#pragma unroll
    for (int r = 0; r < 16; r += 2) {
        const int key = (r & 3) + 8 * (r >> 2) + 4 * h;
        *(uint*)&P_lds[wv][lq][key] = pack2(o16[r], o16[r + 1]);
    }
    const bf16x8 OB0 = *(const bf16x8*)&P_lds[wv][lq][8 * h];       // k = c 0..15
    const bf16x8 OB1 = *(const bf16x8*)&P_lds[wv][lq][16 + 8 * h];  // k = c 16..31

    const float* x_b = x + (size_t)b * CHN * NN;
    float* out_b = out + (size_t)b * CHN * NN;
#pragma unroll
    for (int T = 0; T < 2; ++T) {
        const int row = T * 32 + lq;      // oc row of w_o
        const float* wr = w_o + row * 32;
        float wa[8], wb[8];
#pragma unroll
        for (int j = 0; j < 8; ++j) { wa[j] = wr[8 * h + j]; wb[j] = wr[16 + 8 * h + j]; }
        const bf16x8 A0 = pack8(wa);
        const bf16x8 A1 = pack8(wb);
        f32x16 C2 = __builtin_amdgcn_mfma_f32_32x32x16_bf16(A0, OB0, z16, 0, 0, 0);
        C2 = __builtin_amdgcn_mfma_f32_32x32x16_bf16(A1, OB1, C2, 0, 0, 0);
#pragma unroll
        for (int r = 0; r < 16; ++r) {
            const int oc = T * 32 + (r & 3) + 8 * (r >> 2) + 4 * h;
            const size_t idx = (size_t)oc * NN + q0 + lq;
            out_b[idx] = C2[r] + x_b[idx];
        }
    }
}

// ---------------------------------------------------------------------------
extern "C" void kernel_launch(void* const* d_in, const int* in_sizes, int n_in,
                              void* d_out, int out_size, void* d_ws, size_t ws_size,
                              hipStream_t stream) {
    const float* x       = (const float*)d_in[0];
    const float* w_theta = (const float*)d_in[1];
    const float* w_phi   = (const float*)d_in[2];
    const float* w_g     = (const float*)d_in[3];
    const float* w_o     = (const float*)d_in[4];
    const float* gamma   = (const float*)d_in[5];
    float* out = (float*)d_out;

    ushort* theta_t = (ushort*)d_ws;
    ushort* phi_b   = theta_t + PHI_OFF;
    ushort* gTg     = theta_t + GT_OFF;

    prep_kernel<<<dim3(BB * 256), dim3(64), 0, stream>>>(
        x, w_theta, w_phi, w_g, theta_t, phi_b, gTg);

    attn_mfma<<<dim3(BB * NN / 128), dim3(256), 0, stream>>>(
        x, theta_t, phi_b, gTg, w_o, gamma, out);
}

// Round 10
// 217.128 us; speedup vs baseline: 2.9487x; 1.0336x over previous
//
#include <hip/hip_runtime.h>

typedef unsigned int uint;
typedef unsigned short ushort;
typedef __attribute__((ext_vector_type(8))) short bf16x8;
typedef __attribute__((ext_vector_type(16))) float f32x16;
typedef __attribute__((ext_vector_type(4))) uint uint4v;

constexpr int BB = 4, CHN = 64, HH = 128, WW = 128;
constexpr int NN = HH * WW;              // 16384 queries
constexpr int MM = (HH / 2) * (WW / 2);  // 4096 keys
constexpr float LOG2E = 1.44269504089f;

// workspace offsets in ushort units
constexpr size_t PHI_OFF = (size_t)BB * NN * 8;           // theta: [B][N][8]
constexpr size_t GT_OFF  = PHI_OFF + (size_t)BB * MM * 8; // phi:   [B][M][8]
// gT: [B][M/8][32][8]  (sigma-tiled transpose)

// ---------------------------------------------------------------------------
__device__ __forceinline__ void async16(void* lds_base, const void* gsrc) {
    __builtin_amdgcn_global_load_lds(
        (const __attribute__((address_space(1))) unsigned int*)gsrc,
        (__attribute__((address_space(3))) unsigned int*)lds_base,
        16, 0, 0);
}

__device__ __forceinline__ ushort bf16r(float f) {   // RNE f32->bf16
    uint u = __float_as_uint(f);
    u += 0x7fff + ((u >> 16) & 1);
    return (ushort)(u >> 16);
}

__device__ __forceinline__ uint pack2(float lo, float hi) {
    return (uint)bf16r(lo) | ((uint)bf16r(hi) << 16);
}

__device__ __forceinline__ bf16x8 pack8(const float* v) {
    union { uint4v u; bf16x8 x; } cv;
    cv.u = (uint4v){pack2(v[0], v[1]), pack2(v[2], v[3]),
                    pack2(v[4], v[5]), pack2(v[6], v[7])};
    return cv.x;
}

// ---------------------------------------------------------------------------
// prep (part 0): theta (scaled by log2e) + pooled phi.  (part 1): pooled gT.
// Block = 64 lanes covering a 2-row x 32-col tile of full-res positions.
__global__ __launch_bounds__(64)
void prep_kernel(const float* __restrict__ x,
                 const float* __restrict__ w_theta,
                 const float* __restrict__ w_phi,
                 const float* __restrict__ w_g,
                 ushort* __restrict__ theta_t,
                 ushort* __restrict__ phi_b,
                 ushort* __restrict__ gTg) {
    __shared__ float wlds[32][64];
    const int lane = threadIdx.x;
    const int part = blockIdx.y;
    float* wl = &wlds[0][0];
    if (part == 0) {
        for (int i = lane; i < 512; i += 64) wl[i] = w_theta[i] * LOG2E;
        for (int i = lane; i < 512; i += 64) wl[512 + i] = w_phi[i];
    } else {
        for (int i = lane; i < 2048; i += 64) wl[i] = w_g[i];
    }
    __syncthreads();

    const int bid = blockIdx.x;
    const int b = bid >> 8, tile = bid & 255;
    const int rp = tile >> 2, cb = tile & 3;     // row-pair, col-block
    const int h2 = lane >> 5, w2 = lane & 31;
    const int n = (2 * rp + h2) * WW + 32 * cb + w2;
    const float* xb = x + (size_t)b * CHN * NN + n;
    const int m = rp * 64 + 16 * cb + (w2 >> 1);

    if (part == 0) {
        float acc[16];
#pragma unroll
        for (int k = 0; k < 16; ++k) acc[k] = 0.f;
#pragma unroll 4
        for (int c = 0; c < CHN; ++c) {
            const float xv = xb[(size_t)c * NN];
#pragma unroll
            for (int k = 0; k < 16; ++k) acc[k] = fmaf(wlds[k][c], xv, acc[k]);
        }
        uint4v tv = (uint4v){pack2(acc[0], acc[1]), pack2(acc[2], acc[3]),
                             pack2(acc[4], acc[5]), pack2(acc[6], acc[7])};
        *(uint4v*)(theta_t + ((size_t)b * NN + n) * 8) = tv;
#pragma unroll
        for (int k = 8; k < 16; ++k) {
            float v = acc[k];
            v = fmaxf(v, __shfl_xor(v, 1));
            v = fmaxf(v, __shfl_xor(v, 32));
            acc[k] = v;
        }
        if (h2 == 0 && (w2 & 1) == 0) {
            uint4v pv = (uint4v){pack2(acc[8], acc[9]),   pack2(acc[10], acc[11]),
                                 pack2(acc[12], acc[13]), pack2(acc[14], acc[15])};
            *(uint4v*)(phi_b + ((size_t)b * MM + m) * 8) = pv;
        }
    } else {
        float acc[32];
#pragma unroll
        for (int k = 0; k < 32; ++k) acc[k] = 0.f;
#pragma unroll 4
        for (int c = 0; c < CHN; ++c) {
            const float xv = xb[(size_t)c * NN];
#pragma unroll
            for (int k = 0; k < 32; ++k) acc[k] = fmaf(wlds[k][c], xv, acc[k]);
        }
#pragma unroll
        for (int k = 0; k < 32; ++k) {
            float v = acc[k];
            v = fmaxf(v, __shfl_xor(v, 1));
            v = fmaxf(v, __shfl_xor(v, 32));
            acc[k] = v;
        }
        const int qidx = h2 * 2 + (w2 & 1);
        ushort* gb = gTg + (((size_t)b * (MM / 8) + (m >> 3)) * 32) * 8 + (m & 7);
#pragma unroll
        for (int j = 0; j < 8; ++j) {
            const int c = qidx * 8 + j;
            gb[(size_t)c * 8] = bf16r(acc[c]);
        }
    }
}

// ---------------------------------------------------------------------------
// attn: 4 waves/block; wave (qi,ks) = q-tile qi (32 q), key half ks (2048 keys).
// Flash over the half in 128-key chunks; P/O redistribution via shfl_xor(32).
__global__ __launch_bounds__(256, 4)
void attn_mfma(const float* __restrict__ x,
               const ushort* __restrict__ theta_t,
               const ushort* __restrict__ phi_b,
               const ushort* __restrict__ gTg,
               const float* __restrict__ w_o,
               const float* __restrict__ gamma_p,
               float* __restrict__ out) {
    __shared__ __align__(16) ushort phiL[2][2][1024];  // buf, half: 128 m x 8
    __shared__ __align__(16) ushort gL[2][2][4096];    // buf, half: 16 sig x 32c x 8

    const int tid = threadIdx.x;
    const int wv = tid >> 6, ln = tid & 63;
    const int lq = ln & 31, h = ln >> 5;
    const int ks = wv & 1, qi = wv >> 1;
    const int b = blockIdx.x >> 8;            // 256 blocks per batch
    const int qt = blockIdx.x & 255;
    const int q0 = qt * 64 + qi * 32;

    // theta B-frag: lane holds theta[q0+lq][0..7] (h=1 half killed by A=0)
    union { uint4v u; bf16x8 v; } thc;
    thc.u = *(const uint4v*)(theta_t + ((size_t)b * NN + q0 + lq) * 8);
    const bf16x8 thB = thc.v;

    const char* phiGb = (const char*)(phi_b + (size_t)b * MM * 8);
    const char* gGb   = (const char*)(gTg + (size_t)b * MM * 32);

    f32x16 oacc, z16;
#pragma unroll
    for (int r = 0; r < 16; ++r) { oacc[r] = 0.f; z16[r] = 0.f; }
    float ssum = 0.f;

    auto stage = [&](int t, int buf) {
        for (int p = wv; p < 20; p += 4) {
            const int half = p / 10, pp = p % 10;
            if (pp < 2)
                async16(&phiL[buf][half][pp * 512],
                        phiGb + (size_t)half * 32768 + (size_t)t * 2048 + pp * 1024 + ln * 16);
            else
                async16(&gL[buf][half][(pp - 2) * 512],
                        gGb + (size_t)half * 131072 + (size_t)t * 8192 + (pp - 2) * 1024 + ln * 16);
        }
    };

    stage(0, 0);
    __syncthreads();   // vmcnt(0) + barrier: chunk 0 (both halves) resident

    for (int t = 0; t < 16; ++t) {
        const int buf = t & 1;
        if (t < 15) stage(t + 1, buf ^ 1);   // issue-early (T14)
        const ushort* pL = phiL[buf][ks];
        const ushort* gg = gL[buf][ks];
#pragma unroll
        for (int s = 0; s < 4; ++s) {
            // A = phi tile rows (m = s*32+lq), k = channel; h=1 half = K-pad 0
            bf16x8 aphi = {};
            if (h == 0) aphi = *(const bf16x8*)(pL + (s * 32 + lq) * 8);
            f32x16 S = __builtin_amdgcn_mfma_f32_32x32x16_bf16(aphi, thB, z16, 0, 0, 0);
            float e[16];
#pragma unroll
            for (int r = 0; r < 16; ++r) {
                e[r] = exp2f(fminf(S[r], 60.f));   // theta pre-scaled by log2e
                ssum += e[r];
            }
            // pack pairs: P[i] covers keys {4h,8+4h,16+4h,24+4h}+{0,1}/{2,3}
            uint P[8], sx[8];
#pragma unroll
            for (int i = 0; i < 8; ++i) P[i] = pack2(e[2 * i], e[2 * i + 1]);
#pragma unroll
            for (int i = 0; i < 8; ++i) sx[i] = (uint)__shfl_xor((int)P[i], 32);
            // B-frag: lane (lq,h) needs P[key = 8h+j][q=lq]
            union { uint4v u; bf16x8 v; } B0c, B1c;
            B0c.u = (uint4v){h ? sx[2] : P[0], h ? sx[3] : P[1],
                             h ? P[2] : sx[0], h ? P[3] : sx[1]};
            B1c.u = (uint4v){h ? sx[6] : P[4], h ? sx[7] : P[5],
                             h ? P[6] : sx[4], h ? P[7] : sx[5]};
            const bf16x8 g0 = *(const bf16x8*)(gg + ((s * 4 + h) * 256 + lq * 8));
            const bf16x8 g1 = *(const bf16x8*)(gg + ((s * 4 + 2 + h) * 256 + lq * 8));
            oacc = __builtin_amdgcn_mfma_f32_32x32x16_bf16(g0, B0c.v, oacc, 0, 0, 0);
            oacc = __builtin_amdgcn_mfma_f32_32x32x16_bf16(g1, B1c.v, oacc, 0, 0, 0);
        }
        __syncthreads();   // drains this wave's staged loads + joins waves
    }

    // ---- combine the two K-halves (partner wave), reusing gL as scratch
    ssum += __shfl_xor(ssum, 32);
    float* comb = (float*)&gL[0][0][0];     // 4*64*20*4B = 20,480B < 32KB
    const int my = ((ks * 2 + qi) * 64 + ln) * 20;
#pragma unroll
    for (int r = 0; r < 16; ++r) comb[my + r] = oacc[r];
    comb[my + 16] = ssum;
    __syncthreads();
    const int ot = (((ks ^ 1) * 2 + qi) * 64 + ln) * 20;
#pragma unroll
    for (int r = 0; r < 16; ++r) oacc[r] += comb[ot + r];
    ssum += comb[ot + 16];

    // ---- epilogue: normalize (+gamma), w_o projection via MFMA, residual
    const float sc = gamma_p[0] / fmaxf(ssum, 1e-30f);
    float o16[16];
#pragma unroll
    for (int r = 0; r < 16; ++r) o16[r] = oacc[r] * sc;
    uint OP[8], osx[8];
#pragma unroll
    for (int i = 0; i < 8; ++i) OP[i] = pack2(o16[2 * i], o16[2 * i + 1]);
#pragma unroll
    for (int i = 0; i < 8; ++i) osx[i] = (uint)__shfl_xor((int)OP[i], 32);
    union { uint4v u; bf16x8 v; } OB0c, OB1c;
    OB0c.u = (uint4v){h ? osx[2] : OP[0], h ? osx[3] : OP[1],
                      h ? OP[2] : osx[0], h ? OP[3] : osx[1]};
    OB1c.u = (uint4v){h ? osx[6] : OP[4], h ? osx[7] : OP[5],
                      h ? OP[6] : osx[4], h ? OP[7] : osx[5]};

    const float* x_b = x + (size_t)b * CHN * NN;
    float* out_b = out + (size_t)b * CHN * NN;
    const int T = ks;                       // each K-half wave does one oc-half
    const int row = T * 32 + lq;
    const float* wr = w_o + row * 32;
    float wa[8], wb[8];
#pragma unroll
    for (int j = 0; j < 8; ++j) { wa[j] = wr[8 * h + j]; wb[j] = wr[16 + 8 * h + j]; }
    const bf16x8 A0 = pack8(wa);
    const bf16x8 A1 = pack8(wb);
    f32x16 C2 = __builtin_amdgcn_mfma_f32_32x32x16_bf16(A0, OB0c.v, z16, 0, 0, 0);
    C2 = __builtin_amdgcn_mfma_f32_32x32x16_bf16(A1, OB1c.v, C2, 0, 0, 0);
#pragma unroll
    for (int r = 0; r < 16; ++r) {
        const int oc = T * 32 + (r & 3) + 8 * (r >> 2) + 4 * h;
        const size_t idx = (size_t)oc * NN + q0 + lq;
        out_b[idx] = C2[r] + x_b[idx];
    }
}

// ---------------------------------------------------------------------------
extern "C" void kernel_launch(void* const* d_in, const int* in_sizes, int n_in,
                              void* d_out, int out_size, void* d_ws, size_t ws_size,
                              hipStream_t stream) {
    const float* x       = (const float*)d_in[0];
    const float* w_theta = (const float*)d_in[1];
    const float* w_phi   = (const float*)d_in[2];
    const float* w_g     = (const float*)d_in[3];
    const float* w_o     = (const float*)d_in[4];
    const float* gamma   = (const float*)d_in[5];
    float* out = (float*)d_out;

    ushort* theta_t = (ushort*)d_ws;
    ushort* phi_b   = theta_t + PHI_OFF;
    ushort* gTg     = theta_t + GT_OFF;

    prep_kernel<<<dim3(BB * 256, 2), dim3(64), 0, stream>>>(
        x, w_theta, w_phi, w_g, theta_t, phi_b, gTg);

    attn_mfma<<<dim3(BB * NN / 64), dim3(256), 0, stream>>>(
        x, theta_t, phi_b, gTg, w_o, gamma, out);
}

// Round 11
// 206.003 us; speedup vs baseline: 3.1079x; 1.0540x over previous
//
#include <hip/hip_runtime.h>
#include <hip/hip_bf16.h>

typedef unsigned int uint;
typedef unsigned short ushort;
typedef __attribute__((ext_vector_type(8))) short bf16x8;
typedef __attribute__((ext_vector_type(16))) float f32x16;
typedef __attribute__((ext_vector_type(4))) uint uint4v;

constexpr int BB = 4, CHN = 64, HH = 128, WW = 128;
constexpr int NN = HH * WW;              // 16384 queries
constexpr int MM = (HH / 2) * (WW / 2);  // 4096 keys
constexpr float LOG2E = 1.44269504089f;

// workspace offsets in ushort units
constexpr size_t PHI_OFF = (size_t)BB * NN * 8;           // theta: [B][N][8]
constexpr size_t GT_OFF  = PHI_OFF + (size_t)BB * MM * 8; // phi:   [B][M][8]
// gT: [B][M/32 tiles][1024]  permuted-transposed: slot (M,h,c,j) = M*512+h*256+c*8+j
// holds g[c][key(M,h,j)] with key(M,h,j) = 16M + 8*(j>=4) + 4h + (j&3)

// ---------------------------------------------------------------------------
__device__ __forceinline__ void async16(void* lds_base, const void* gsrc) {
    __builtin_amdgcn_global_load_lds(
        (const __attribute__((address_space(1))) unsigned int*)gsrc,
        (__attribute__((address_space(3))) unsigned int*)lds_base,
        16, 0, 0);
}

__device__ __forceinline__ ushort bf16r(float f) {   // RNE f32->bf16
    uint u = __float_as_uint(f);
    u += 0x7fff + ((u >> 16) & 1);
    return (ushort)(u >> 16);
}

__device__ __forceinline__ uint pk2(float lo, float hi) {  // v_cvt_pk_bf16_f32 path
    union { __hip_bfloat162 h; uint u; } cv;
    cv.h = __float22bfloat162_rn(make_float2(lo, hi));
    return cv.u;
}

__device__ __forceinline__ bf16x8 pk8(const float* v) {
    union { uint4v u; bf16x8 x; } cv;
    cv.u = (uint4v){pk2(v[0], v[1]), pk2(v[2], v[3]),
                    pk2(v[4], v[5]), pk2(v[6], v[7])};
    return cv.x;
}

// ---------------------------------------------------------------------------
// prep (part 0): theta (scaled by log2e) + pooled phi.  (part 1): pooled gT
// in the k-slot-permuted layout, staged in LDS for one coalesced wave store.
__global__ __launch_bounds__(64)
void prep_kernel(const float* __restrict__ x,
                 const float* __restrict__ w_theta,
                 const float* __restrict__ w_phi,
                 const float* __restrict__ w_g,
                 ushort* __restrict__ theta_t,
                 ushort* __restrict__ phi_b,
                 ushort* __restrict__ gTg) {
    __shared__ float wlds[32][64];
    __shared__ __align__(16) ushort stg[512];
    const int lane = threadIdx.x;
    const int part = blockIdx.y;
    float* wl = &wlds[0][0];
    if (part == 0) {
        for (int i = lane; i < 512; i += 64) wl[i] = w_theta[i] * LOG2E;
        for (int i = lane; i < 512; i += 64) wl[512 + i] = w_phi[i];
    } else {
        for (int i = lane; i < 2048; i += 64) wl[i] = w_g[i];
    }
    __syncthreads();

    const int bid = blockIdx.x;
    const int b = bid >> 8, tile = bid & 255;
    const int rp = tile >> 2, cb = tile & 3;     // row-pair, col-block
    const int h2 = lane >> 5, w2 = lane & 31;
    const int n = (2 * rp + h2) * WW + 32 * cb + w2;
    const float* xb = x + (size_t)b * CHN * NN + n;
    const int m = rp * 64 + 16 * cb + (w2 >> 1);

    if (part == 0) {
        float acc[16];
#pragma unroll
        for (int k = 0; k < 16; ++k) acc[k] = 0.f;
#pragma unroll 4
        for (int c = 0; c < CHN; ++c) {
            const float xv = xb[(size_t)c * NN];
#pragma unroll
            for (int k = 0; k < 16; ++k) acc[k] = fmaf(wlds[k][c], xv, acc[k]);
        }
        uint4v tv = (uint4v){pk2(acc[0], acc[1]), pk2(acc[2], acc[3]),
                             pk2(acc[4], acc[5]), pk2(acc[6], acc[7])};
        *(uint4v*)(theta_t + ((size_t)b * NN + n) * 8) = tv;
#pragma unroll
        for (int k = 8; k < 16; ++k) {
            float v = acc[k];
            v = fmaxf(v, __shfl_xor(v, 1));
            v = fmaxf(v, __shfl_xor(v, 32));
            acc[k] = v;
        }
        if (h2 == 0 && (w2 & 1) == 0) {
            uint4v pv = (uint4v){pk2(acc[8], acc[9]),   pk2(acc[10], acc[11]),
                                 pk2(acc[12], acc[13]), pk2(acc[14], acc[15])};
            *(uint4v*)(phi_b + ((size_t)b * MM + m) * 8) = pv;
        }
    } else {
        float acc[32];
#pragma unroll
        for (int k = 0; k < 32; ++k) acc[k] = 0.f;
#pragma unroll 4
        for (int c = 0; c < CHN; ++c) {
            const float xv = xb[(size_t)c * NN];
#pragma unroll
            for (int k = 0; k < 32; ++k) acc[k] = fmaf(wlds[k][c], xv, acc[k]);
        }
#pragma unroll
        for (int k = 0; k < 32; ++k) {
            float v = acc[k];
            v = fmaxf(v, __shfl_xor(v, 1));
            v = fmaxf(v, __shfl_xor(v, 32));
            acc[k] = v;
        }
        // permuted in-tile slot for this m: inverse of key(M,h,j)
        const int mm = w2 >> 1;                       // m & 15
        const int hp = (mm >> 2) & 1;                 // h slot
        const int jp = (mm & 3) + 4 * ((mm >> 3) & 1);// j slot
        const int qidx = h2 * 2 + (w2 & 1);
#pragma unroll
        for (int j = 0; j < 8; ++j) {
            const int c = qidx * 8 + j;
            stg[hp * 256 + c * 8 + jp] = bf16r(acc[c]);
        }
        // coalesced wave store of the 512-ushort subtile (M = cb&1 uniform)
        const int tl = rp * 2 + (cb >> 1);            // m >> 5
        const int M = cb & 1;
        uint4v val = *(uint4v*)&stg[lane * 8];
        *(uint4v*)(gTg + ((size_t)b * (MM / 32) + tl) * 1024 + M * 512 + lane * 8) = val;
    }
}

// ---------------------------------------------------------------------------
// attn: 4 waves/block; wave (qi,ks) = q-tile qi (32 q), key half ks (2048 keys).
// Flash over the half in 128-key chunks. k-slot-permuted g layout makes the
// P B-frag = lane-local C registers (no cross-lane exchange at all).
__global__ __launch_bounds__(256, 4)
void attn_mfma(const float* __restrict__ x,
               const ushort* __restrict__ theta_t,
               const ushort* __restrict__ phi_b,
               const ushort* __restrict__ gTg,
               const float* __restrict__ w_o,
               const float* __restrict__ gamma_p,
               float* __restrict__ out) {
    __shared__ __align__(16) ushort phiL[2][2][1024];  // buf, half: 128 m x 8
    __shared__ __align__(16) ushort gL[2][2][4096];    // buf, half: 4 tiles x 1024

    const int tid = threadIdx.x;
    const int wv = tid >> 6, ln = tid & 63;
    const int lq = ln & 31, h = ln >> 5;
    const int ks = wv & 1, qi = wv >> 1;
    const int b = blockIdx.x >> 8;            // 256 blocks per batch
    const int qt = blockIdx.x & 255;
    const int q0 = qt * 64 + qi * 32;

    // theta B-frag: lane holds theta[q0+lq][0..7] (h=1 half killed by A=0)
    union { uint4v u; bf16x8 v; } thc;
    thc.u = *(const uint4v*)(theta_t + ((size_t)b * NN + q0 + lq) * 8);
    const bf16x8 thB = thc.v;

    const char* phiGb = (const char*)(phi_b + (size_t)b * MM * 8);
    const char* gGb   = (const char*)(gTg + (size_t)b * MM * 32);

    f32x16 oacc, z16;
#pragma unroll
    for (int r = 0; r < 16; ++r) { oacc[r] = 0.f; z16[r] = 0.f; }
    float ssum = 0.f;

    auto stage = [&](int t, int buf) {
        for (int p = wv; p < 20; p += 4) {
            const int half = p / 10, pp = p % 10;
            if (pp < 2)
                async16(&phiL[buf][half][pp * 512],
                        phiGb + (size_t)half * 32768 + (size_t)t * 2048 + pp * 1024 + ln * 16);
            else
                async16(&gL[buf][half][(pp - 2) * 512],
                        gGb + (size_t)half * 131072 + (size_t)t * 8192 + (pp - 2) * 1024 + ln * 16);
        }
    };

    stage(0, 0);
    __syncthreads();   // vmcnt(0) + barrier: chunk 0 (both halves) resident

    for (int t = 0; t < 16; ++t) {
        const int buf = t & 1;
        if (t < 15) stage(t + 1, buf ^ 1);   // issue-early (T14)
        const ushort* pL = phiL[buf][ks];
        const ushort* gg = gL[buf][ks];
#pragma unroll
        for (int s = 0; s < 4; ++s) {
            // A = phi tile rows (m = s*32+lq), k = channel; h=1 half = K-pad 0
            bf16x8 aphi = {};
            if (h == 0) aphi = *(const bf16x8*)(pL + (s * 32 + lq) * 8);
            f32x16 S = __builtin_amdgcn_mfma_f32_32x32x16_bf16(aphi, thB, z16, 0, 0, 0);
            float e[16];
#pragma unroll
            for (int r = 0; r < 16; ++r) {
                e[r] = exp2f(fminf(S[r], 60.f));   // theta pre-scaled by log2e
                ssum += e[r];
            }
            // B-frags are lane-local: slot order == C-register order
            const bf16x8 B0 = pk8(e);
            const bf16x8 B1 = pk8(e + 8);
            const bf16x8 g0 = *(const bf16x8*)(gg + (s * 1024 + h * 256 + lq * 8));
            const bf16x8 g1 = *(const bf16x8*)(gg + (s * 1024 + 512 + h * 256 + lq * 8));
            oacc = __builtin_amdgcn_mfma_f32_32x32x16_bf16(g0, B0, oacc, 0, 0, 0);
            oacc = __builtin_amdgcn_mfma_f32_32x32x16_bf16(g1, B1, oacc, 0, 0, 0);
        }
        __syncthreads();   // drains this wave's staged loads + joins waves
    }

    // ---- combine the two K-halves (partner wave), reusing gL as scratch
    ssum += __shfl_xor(ssum, 32);
    float* comb = (float*)&gL[0][0][0];     // 4*64*20*4B = 20,480B < 32KB
    const int my = ((ks * 2 + qi) * 64 + ln) * 20;
#pragma unroll
    for (int r = 0; r < 16; ++r) comb[my + r] = oacc[r];
    comb[my + 16] = ssum;
    __syncthreads();
    const int ot = (((ks ^ 1) * 2 + qi) * 64 + ln) * 20;
#pragma unroll
    for (int r = 0; r < 16; ++r) oacc[r] += comb[ot + r];
    ssum += comb[ot + 16];

    // ---- epilogue: normalize (+gamma), w_o projection via MFMA, residual
    const float sc = gamma_p[0] / fmaxf(ssum, 1e-30f);
    float o16[16];
#pragma unroll
    for (int r = 0; r < 16; ++r) o16[r] = oacc[r] * sc;
    // O B-frag is lane-local with the same k-slot permutation; w_o A-frag
    // picks the matching channels: ch(h,j) = 8*(j>=4) + 4h + (j&3)
    const bf16x8 OB0 = pk8(o16);
    const bf16x8 OB1 = pk8(o16 + 8);

    const float* x_b = x + (size_t)b * CHN * NN;
    float* out_b = out + (size_t)b * CHN * NN;
    const int T = ks;                       // each K-half wave does one oc-half
    const int row = T * 32 + lq;
    const float* wr = w_o + row * 32;
    float wa[8], wb[8];
#pragma unroll
    for (int j = 0; j < 8; ++j) {
        const int ch = 8 * (j >> 2) + 4 * h + (j & 3);
        wa[j] = wr[ch];
        wb[j] = wr[16 + ch];
    }
    const bf16x8 A0 = pk8(wa);
    const bf16x8 A1 = pk8(wb);
    f32x16 C2 = __builtin_amdgcn_mfma_f32_32x32x16_bf16(A0, OB0, z16, 0, 0, 0);
    C2 = __builtin_amdgcn_mfma_f32_32x32x16_bf16(A1, OB1, C2, 0, 0, 0);
#pragma unroll
    for (int r = 0; r < 16; ++r) {
        const int oc = T * 32 + (r & 3) + 8 * (r >> 2) + 4 * h;
        const size_t idx = (size_t)oc * NN + q0 + lq;
        out_b[idx] = C2[r] + x_b[idx];
    }
}

// ---------------------------------------------------------------------------
extern "C" void kernel_launch(void* const* d_in, const int* in_sizes, int n_in,
                              void* d_out, int out_size, void* d_ws, size_t ws_size,
                              hipStream_t stream) {
    const float* x       = (const float*)d_in[0];
    const float* w_theta = (const float*)d_in[1];
    const float* w_phi   = (const float*)d_in[2];
    const float* w_g     = (const float*)d_in[3];
    const float* w_o     = (const float*)d_in[4];
    const float* gamma   = (const float*)d_in[5];
    float* out = (float*)d_out;

    ushort* theta_t = (ushort*)d_ws;
    ushort* phi_b   = theta_t + PHI_OFF;
    ushort* gTg     = theta_t + GT_OFF;

    prep_kernel<<<dim3(BB * 256, 2), dim3(64), 0, stream>>>(
        x, w_theta, w_phi, w_g, theta_t, phi_b, gTg);

    attn_mfma<<<dim3(BB * NN / 64), dim3(256), 0, stream>>>(
        x, theta_t, phi_b, gTg, w_o, gamma, out);
}